// Round 2
// baseline (747.150 us; speedup 1.0000x reference)
//
#include <hip/hip_runtime.h>

#define HID 256
#define EPSV 1e-5f
#define ASTR 72   // layer-0 At row stride (ushorts): 64 data + 8 pad
#define BSTR 40   // 32 data + 8 pad

typedef __bf16 bf16x8 __attribute__((ext_vector_type(8)));
typedef float  floatx4 __attribute__((ext_vector_type(4)));

static __device__ __forceinline__ ushort f2bf(float f) {
  union { float f; unsigned int i; } c; c.f = f;
  unsigned int u = c.i;
  u += 0x7FFFu + ((u >> 16) & 1u);   // round-to-nearest-even
  return (ushort)(u >> 16);
}
static __device__ __forceinline__ float bf2f(ushort u) {
  union { unsigned int i; float f; } c; c.i = ((unsigned int)u) << 16; return c.f;
}

// ---------------- CSR build ----------------
__global__ void count_kernel(const int* __restrict__ ei, int* __restrict__ deg, int E, int tot) {
  int i = blockIdx.x * blockDim.x + threadIdx.x;
  if (i < tot) {
    int dst = (i < E) ? ei[E + i] : (i - E);
    atomicAdd(&deg[dst], 1);
  }
}

// hierarchical exclusive scan of deg -> rp
__global__ void scanA_kernel(const int* __restrict__ deg, int* __restrict__ incl,
                             int* __restrict__ sums, int n) {
  __shared__ int buf[1024];
  const int t = threadIdx.x;
  const int i = blockIdx.x * 1024 + t;
  int x = (i < n) ? deg[i] : 0;
  buf[t] = x;
  __syncthreads();
  for (int off = 1; off < 1024; off <<= 1) {
    int v = (t >= off) ? buf[t - off] : 0;
    __syncthreads();
    buf[t] += v;
    __syncthreads();
  }
  if (i < n) incl[i] = buf[t];
  if (t == 1023) sums[blockIdx.x] = buf[1023];
}

__global__ void scanB_kernel(int* __restrict__ sums, int* __restrict__ offs, int nblk) {
  __shared__ int buf[256];
  const int t = threadIdx.x;
  int x = (t < nblk) ? sums[t] : 0;
  buf[t] = x;
  __syncthreads();
  for (int off = 1; off < 256; off <<= 1) {
    int v = (t >= off) ? buf[t - off] : 0;
    __syncthreads();
    buf[t] += v;
    __syncthreads();
  }
  if (t < nblk) offs[t] = buf[t] - x;   // exclusive
  if (t == nblk) offs[nblk] = buf[nblk - 1];  // grand total
}

__global__ void scanC_kernel(const int* __restrict__ deg, const int* __restrict__ incl,
                             const int* __restrict__ offs, int* __restrict__ rp,
                             int* __restrict__ cur, int n, int nblk) {
  const int i = blockIdx.x * 1024 + threadIdx.x;
  if (i < n) {
    int v = offs[blockIdx.x] + incl[i] - deg[i];
    rp[i] = v;
    cur[i] = v;
  }
  if (i == 0) rp[n] = offs[nblk];
}

__global__ void scatter_kernel(const int* __restrict__ ei, int* __restrict__ cur,
                               int* __restrict__ csr, int E, int tot) {
  int i = blockIdx.x * blockDim.x + threadIdx.x;
  if (i < tot) {
    int src = (i < E) ? ei[i] : (i - E);
    int dst = (i < E) ? ei[E + i] : (i - E);
    int pos = atomicAdd(&cur[dst], 1);
    csr[pos] = src;
  }
}

// ---------------- W transpose + bf16 cast: f32 [K][256] -> bf16 [256][K] ----------------
// LDS-tiled 32x32: coalesced reads AND writes (old version wrote 2B at stride K).
__global__ __launch_bounds__(256) void transpose_kernel(
    const float* __restrict__ W, ushort* __restrict__ Wt, int K) {
  __shared__ ushort tile[32][33];
  const int tx = threadIdx.x & 31, ty = threadIdx.x >> 5;   // 32 x 8
  const int bm = blockIdx.x * 32;   // m block (cols of W, rows of Wt)
  const int bk = blockIdx.y * 32;   // k block
  #pragma unroll
  for (int yy = ty; yy < 32; yy += 8)
    tile[tx][yy] = f2bf(W[(size_t)(bk + yy) * 256 + bm + tx]);
  __syncthreads();
  #pragma unroll
  for (int yy = ty; yy < 32; yy += 8)
    Wt[(size_t)(bm + yy) * K + bk + tx] = tile[yy][tx];
}

// ---- fused alpha-dot epilogue: acc rows dotted with a_src/a_dst col-spans ----
// Each wave's row span is 64 consecutive cols. Always writes partial slot
// (col0+wn)>>6 in [0,4): == head for H=4, == 64-col partial for H=1 (agg sums 4).
static __device__ __forceinline__ void alpha_epilogue(
    const floatx4 (&acc)[4][4], const float* __restrict__ avs,
    const float* __restrict__ avd, float* __restrict__ asrc,
    float* __restrict__ adst, int row0, int col0, int wm, int wn,
    int quad, int m16, int nrows) {
  float sv[4], dv[4];
  #pragma unroll
  for (int j = 0; j < 4; j++) {
    int col = col0 + wn + j * 16 + m16;
    sv[j] = avs[col];
    dv[j] = avd[col];
  }
  const int idx = (col0 + wn) >> 6;   // 0..3
  #pragma unroll
  for (int i = 0; i < 4; i++) {
    #pragma unroll
    for (int r = 0; r < 4; r++) {
      int row = row0 + wm + i * 16 + quad * 4 + r;
      float s = 0.f, d = 0.f;
      #pragma unroll
      for (int j = 0; j < 4; j++) {
        s = fmaf(acc[i][j][r], sv[j], s);
        d = fmaf(acc[i][j][r], dv[j], d);
      }
      #pragma unroll
      for (int o = 1; o < 16; o <<= 1) { s += __shfl_xor(s, o); d += __shfl_xor(d, o); }
      if (m16 == 0 && row < nrows) {
        asrc[row * 4 + idx] = s;
        adst[row * 4 + idx] = d;
      }
    }
  }
}

// ---------------- GEMM (layer 0): hb = A_f32[nrows,512] @ W ----------------
// Reg-staged 2-phase pipeline: next tile's global loads issue before this
// tile's MFMA (register loads survive s_barrier -> latency hides under compute).
// hi/lo split via truncation: hi = v_perm pack of high16, lo = v - (u&0xffff0000)
// then truncate again. Error <= 2^-16 rel; ~4x fewer VALU than RNE f2bf.
__global__ __launch_bounds__(256) void gemm_kernel(
    const float* __restrict__ A, const ushort* __restrict__ Bt,
    ushort* __restrict__ hb, const float* __restrict__ avs,
    const float* __restrict__ avd, float* __restrict__ asrc,
    float* __restrict__ adst, int nrows, int K) {
  __shared__ ushort At[128 * ASTR];
  __shared__ ushort Bs[128 * BSTR];
  const int tid  = threadIdx.x;
  const int lane = tid & 63;
  const int wave = tid >> 6;
  const int quad = lane >> 4;
  const int m16  = lane & 15;
  const int row0 = blockIdx.x * 128;
  const int col0 = blockIdx.y * 128;
  const int wm = (wave >> 1) * 64;
  const int wn = (wave & 1) * 64;

  floatx4 acc[4][4];
  #pragma unroll
  for (int i = 0; i < 4; i++)
    #pragma unroll
    for (int j = 0; j < 4; j++) acc[i][j] = (floatx4){0.f, 0.f, 0.f, 0.f};

  const int arow = tid >> 3;
  const int acol = (tid & 7) * 4;
  const int brow = tid >> 2;
  const int bcol = (tid & 3) * 8;

  const float* pa[4];
  const ushort* pb[2];
  #pragma unroll
  for (int i = 0; i < 4; i++) {
    int r = arow + 32 * i;
    int ar = min(row0 + r, nrows - 1);
    pa[i] = A + (size_t)ar * K + acol;
  }
  #pragma unroll
  for (int i = 0; i < 2; i++)
    pb[i] = Bt + (size_t)(col0 + brow + 64 * i) * K + bcol;

  floatx4 rA[4];
  int4 rB[2];
  #pragma unroll
  for (int i = 0; i < 4; i++) rA[i] = *(const floatx4*)pa[i];
  #pragma unroll
  for (int i = 0; i < 2; i++) rB[i] = *(const int4*)pb[i];

  for (int k0 = 0; k0 < K; k0 += 32) {
    // stage current regs -> LDS
    #pragma unroll
    for (int i = 0; i < 4; i++) {
      int r = arow + 32 * i;
      floatx4 v = rA[i];
      unsigned u0 = __float_as_uint(v[0]), u1 = __float_as_uint(v[1]);
      unsigned u2 = __float_as_uint(v[2]), u3 = __float_as_uint(v[3]);
      unsigned ph0 = __builtin_amdgcn_perm(u1, u0, 0x07060302u);
      unsigned ph1 = __builtin_amdgcn_perm(u3, u2, 0x07060302u);
      float l0 = v[0] - __uint_as_float(u0 & 0xffff0000u);
      float l1 = v[1] - __uint_as_float(u1 & 0xffff0000u);
      float l2 = v[2] - __uint_as_float(u2 & 0xffff0000u);
      float l3 = v[3] - __uint_as_float(u3 & 0xffff0000u);
      unsigned pl0 = __builtin_amdgcn_perm(__float_as_uint(l1), __float_as_uint(l0), 0x07060302u);
      unsigned pl1 = __builtin_amdgcn_perm(__float_as_uint(l3), __float_as_uint(l2), 0x07060302u);
      *(uint2*)&At[r * ASTR + acol]      = make_uint2(ph0, ph1);
      *(uint2*)&At[r * ASTR + 32 + acol] = make_uint2(pl0, pl1);
    }
    #pragma unroll
    for (int i = 0; i < 2; i++)
      *(int4*)&Bs[(brow + 64 * i) * BSTR + bcol] = rB[i];
    __syncthreads();
    // issue next tile's loads (regs only -> no barrier drain)
    if (k0 + 32 < K) {
      #pragma unroll
      for (int i = 0; i < 4; i++) rA[i] = *(const floatx4*)(pa[i] + k0 + 32);
      #pragma unroll
      for (int i = 0; i < 2; i++) rB[i] = *(const int4*)(pb[i] + k0 + 32);
    }
    // compute from LDS
    bf16x8 bfr[4];
    #pragma unroll
    for (int j = 0; j < 4; j++)
      bfr[j] = *(const bf16x8*)&Bs[(wn + j * 16 + m16) * BSTR + quad * 8];
    #pragma unroll
    for (int p = 0; p < 2; p++) {
      bf16x8 af[4];
      #pragma unroll
      for (int i = 0; i < 4; i++)
        af[i] = *(const bf16x8*)&At[(wm + i * 16 + m16) * ASTR + p * 32 + quad * 8];
      #pragma unroll
      for (int i = 0; i < 4; i++)
        #pragma unroll
        for (int j = 0; j < 4; j++)
          acc[i][j] = __builtin_amdgcn_mfma_f32_16x16x32_bf16(af[i], bfr[j], acc[i][j], 0, 0, 0);
    }
    __syncthreads();
  }
  #pragma unroll
  for (int i = 0; i < 4; i++) {
    int rbase = row0 + wm + i * 16 + quad * 4;
    #pragma unroll
    for (int j = 0; j < 4; j++) {
      int col = col0 + wn + j * 16 + m16;
      #pragma unroll
      for (int r = 0; r < 4; r++) {
        int row = rbase + r;
        if (row < nrows) hb[(size_t)row * HID + col] = f2bf(acc[i][j][r]);
      }
    }
  }
  alpha_epilogue(acc, avs, avd, asrc, adst, row0, col0, wm, wn, quad, m16, nrows);
}

// ---------------- GEMM (layers 1-2): hb = apk[nrows,512](hi|lo) @ W-replicated ----------------
__global__ __launch_bounds__(256) void gemm_packed_kernel(
    const ushort* __restrict__ A, const ushort* __restrict__ Bt,
    ushort* __restrict__ hb, const float* __restrict__ avs,
    const float* __restrict__ avd, float* __restrict__ asrc,
    float* __restrict__ adst, int nrows) {
  __shared__ ushort At[128 * BSTR];
  __shared__ ushort Bs[128 * BSTR];
  const int tid  = threadIdx.x;
  const int lane = tid & 63;
  const int wave = tid >> 6;
  const int quad = lane >> 4;
  const int m16  = lane & 15;
  const int row0 = blockIdx.x * 128;
  const int col0 = blockIdx.y * 128;
  const int wm = (wave >> 1) * 64;
  const int wn = (wave & 1) * 64;

  floatx4 acc[4][4];
  #pragma unroll
  for (int i = 0; i < 4; i++)
    #pragma unroll
    for (int j = 0; j < 4; j++) acc[i][j] = (floatx4){0.f, 0.f, 0.f, 0.f};

  const int srow = tid >> 2;
  const int scol = (tid & 3) * 8;

  const ushort* pa[2];
  const ushort* pb[2];
  #pragma unroll
  for (int i = 0; i < 2; i++) {
    int r = srow + 64 * i;
    int ar = min(row0 + r, nrows - 1);
    pa[i] = A + (size_t)ar * 512 + scol;
    pb[i] = Bt + (size_t)(col0 + r) * 256 + scol;
  }

  int4 rA[2], rB[2];
  #pragma unroll
  for (int i = 0; i < 2; i++) { rA[i] = *(const int4*)pa[i]; rB[i] = *(const int4*)pb[i]; }

  for (int k0 = 0; k0 < 512; k0 += 32) {
    #pragma unroll
    for (int i = 0; i < 2; i++) {
      int r = srow + 64 * i;
      *(int4*)&At[r * BSTR + scol] = rA[i];
      *(int4*)&Bs[r * BSTR + scol] = rB[i];
    }
    __syncthreads();
    if (k0 + 32 < 512) {
      int kn = k0 + 32, kbn = kn & 255;
      #pragma unroll
      for (int i = 0; i < 2; i++) {
        rA[i] = *(const int4*)(pa[i] + kn);
        rB[i] = *(const int4*)(pb[i] + kbn);
      }
    }
    bf16x8 af[4], bfr[4];
    #pragma unroll
    for (int j = 0; j < 4; j++)
      bfr[j] = *(const bf16x8*)&Bs[(wn + j * 16 + m16) * BSTR + quad * 8];
    #pragma unroll
    for (int i = 0; i < 4; i++)
      af[i] = *(const bf16x8*)&At[(wm + i * 16 + m16) * BSTR + quad * 8];
    #pragma unroll
    for (int i = 0; i < 4; i++)
      #pragma unroll
      for (int j = 0; j < 4; j++)
        acc[i][j] = __builtin_amdgcn_mfma_f32_16x16x32_bf16(af[i], bfr[j], acc[i][j], 0, 0, 0);
    __syncthreads();
  }
  #pragma unroll
  for (int i = 0; i < 4; i++) {
    int rbase = row0 + wm + i * 16 + quad * 4;
    #pragma unroll
    for (int j = 0; j < 4; j++) {
      int col = col0 + wn + j * 16 + m16;
      #pragma unroll
      for (int r = 0; r < 4; r++) {
        int row = rbase + r;
        if (row < nrows) hb[(size_t)row * HID + col] = f2bf(acc[i][j][r]);
      }
    }
  }
  alpha_epilogue(acc, avs, avd, asrc, adst, row0, col0, wm, wn, quad, m16, nrows);
}

// ---- fused segment softmax + aggregation + bias + LayerNorm + ELU ----
// ONE WAVE PER NODE, 4 ch/lane. Phase B unrolled x4 (4 gathers in flight).
// For H=1, asrc/adst hold 4 partials per node (written by alpha_epilogue)
// -> summed here; no atomics, no memset.
__global__ __launch_bounds__(256) void agg_ln_kernel(
    const ushort* __restrict__ hb, const float* __restrict__ asrc,
    const float* __restrict__ adst, const int* __restrict__ rp,
    const int* __restrict__ csr,
    const float* __restrict__ bias, const float* __restrict__ lnw,
    const float* __restrict__ lnb, ushort* __restrict__ apk,
    float* __restrict__ fout, int H, int n) {
  __shared__ float2 exs[4][64];
  const int t = threadIdx.x;
  const int w = t >> 6, lane = t & 63;
  const int nid = blockIdx.x * 4 + w;
  if (nid >= n) return;
  const int CH = (H == 4) ? 16 : 64;   // edges per chunk
  const int jj = lane & (CH - 1);
  const int hh = (H == 4) ? (lane >> 4) : 0;
  const int ch = 4 * lane;
  float ad;
  if (H == 4) {
    ad = adst[nid * 4 + hh];
  } else {
    floatx4 t4 = *(const floatx4*)(adst + nid * 4);
    ad = t4[0] + t4[1] + t4[2] + t4[3];
  }
  const int beg = rp[nid], end = rp[nid + 1];
  const char* hbase = (const char*)hb + ch * 2;
  float den = 0.f;
  float a0 = 0.f, a1 = 0.f, a2 = 0.f, a3 = 0.f;
  float b0 = 0.f, b1 = 0.f, b2 = 0.f, b3 = 0.f;
  float c0_ = 0.f, c1 = 0.f, c2 = 0.f, c3 = 0.f;
  float d0_ = 0.f, d1 = 0.f, d2 = 0.f, d3 = 0.f;

  // preload first chunk's csr
  int snext = 0;
  {
    int cnt0 = min(CH, end - beg);
    if (lane < cnt0) snext = csr[beg + lane];
  }

  for (int c0 = beg; c0 < end; c0 += CH) {
    const int cnt = min(CH, end - c0);
    int s = snext;
    // prefetch next chunk's csr while this chunk computes
    const int nc0 = c0 + CH;
    if (nc0 < end) {
      int ncnt = min(CH, end - nc0);
      if (lane < ncnt) snext = csr[nc0 + lane];
    }
    // phase A
    s = __shfl(s, jj);
    float ex = 0.f;
    if (jj < cnt) {
      float e;
      if (H == 4) {
        e = asrc[s * 4 + hh] + ad;
      } else {
        floatx4 t4 = *(const floatx4*)(asrc + s * 4);
        e = t4[0] + t4[1] + t4[2] + t4[3] + ad;
      }
      e = (e > 0.f) ? e : 0.2f * e;    // leaky_relu 0.2
      ex = __expf(fminf(e, 60.f));
    }
    exs[w][lane] = make_float2(ex, __int_as_float(s << 9));
    float dsum = ex;
    #pragma unroll
    for (int o = 32; o > 0; o >>= 1)
      if (o < CH) dsum += __shfl_xor(dsum, o);
    den += dsum;
    // phase B: unroll x4, 4 accumulator quads, 4 gathers in flight
    const float2* exw = &exs[w][hh * CH];
    int j = 0;
    for (; j + 4 <= cnt; j += 4) {
      float2 q0 = exw[j];
      float2 q1 = exw[j + 1];
      float2 q2 = exw[j + 2];
      float2 q3 = exw[j + 3];
      uint2 u0 = *(const uint2*)(hbase + __float_as_int(q0.y));
      uint2 u1 = *(const uint2*)(hbase + __float_as_int(q1.y));
      uint2 u2 = *(const uint2*)(hbase + __float_as_int(q2.y));
      uint2 u3 = *(const uint2*)(hbase + __float_as_int(q3.y));
      a0 = fmaf(q0.x, __uint_as_float(u0.x << 16), a0);
      a1 = fmaf(q0.x, __uint_as_float(u0.x & 0xffff0000u), a1);
      a2 = fmaf(q0.x, __uint_as_float(u0.y << 16), a2);
      a3 = fmaf(q0.x, __uint_as_float(u0.y & 0xffff0000u), a3);
      b0 = fmaf(q1.x, __uint_as_float(u1.x << 16), b0);
      b1 = fmaf(q1.x, __uint_as_float(u1.x & 0xffff0000u), b1);
      b2 = fmaf(q1.x, __uint_as_float(u1.y << 16), b2);
      b3 = fmaf(q1.x, __uint_as_float(u1.y & 0xffff0000u), b3);
      c0_ = fmaf(q2.x, __uint_as_float(u2.x << 16), c0_);
      c1 = fmaf(q2.x, __uint_as_float(u2.x & 0xffff0000u), c1);
      c2 = fmaf(q2.x, __uint_as_float(u2.y << 16), c2);
      c3 = fmaf(q2.x, __uint_as_float(u2.y & 0xffff0000u), c3);
      d0_ = fmaf(q3.x, __uint_as_float(u3.x << 16), d0_);
      d1 = fmaf(q3.x, __uint_as_float(u3.x & 0xffff0000u), d1);
      d2 = fmaf(q3.x, __uint_as_float(u3.y << 16), d2);
      d3 = fmaf(q3.x, __uint_as_float(u3.y & 0xffff0000u), d3);
    }
    for (; j < cnt; ++j) {
      float2 q0 = exw[j];
      uint2 u0 = *(const uint2*)(hbase + __float_as_int(q0.y));
      a0 = fmaf(q0.x, __uint_as_float(u0.x << 16), a0);
      a1 = fmaf(q0.x, __uint_as_float(u0.x & 0xffff0000u), a1);
      a2 = fmaf(q0.x, __uint_as_float(u0.y << 16), a2);
      a3 = fmaf(q0.x, __uint_as_float(u0.y & 0xffff0000u), a3);
    }
  }
  a0 += b0 + c0_ + d0_;
  a1 += b1 + c1 + d1;
  a2 += b2 + c2 + d2;
  a3 += b3 + c3 + d3;

  // epilogue: bias + LN + ELU (wave-local, barrier-free)
  const float inv = 1.f / den;
  const floatx4 bia = *(const floatx4*)(bias + ch);
  float v0 = a0 * inv + bia[0];
  float v1 = a1 * inv + bia[1];
  float v2 = a2 * inv + bia[2];
  float v3 = a3 * inv + bia[3];
  float r1 = v0 + v1 + v2 + v3;
  #pragma unroll
  for (int o = 32; o > 0; o >>= 1) r1 += __shfl_xor(r1, o);
  float mu = r1 * (1.f / HID);
  float e0 = v0 - mu, e1 = v1 - mu, e2 = v2 - mu, e3 = v3 - mu;
  float r2 = e0 * e0 + e1 * e1 + e2 * e2 + e3 * e3;
  #pragma unroll
  for (int o = 32; o > 0; o >>= 1) r2 += __shfl_xor(r2, o);
  float rstd = rsqrtf(r2 * (1.f / HID) + EPSV);
  const floatx4 wv = *(const floatx4*)(lnw + ch);
  const floatx4 bv = *(const floatx4*)(lnb + ch);
  float y0 = e0 * rstd * wv[0] + bv[0];
  float y1 = e1 * rstd * wv[1] + bv[1];
  float y2 = e2 * rstd * wv[2] + bv[2];
  float y3 = e3 * rstd * wv[3] + bv[3];
  float o0 = (y0 > 0.f) ? y0 : expm1f(y0);   // ELU
  float o1 = (y1 > 0.f) ? y1 : expm1f(y1);
  float o2 = (y2 > 0.f) ? y2 : expm1f(y2);
  float o3 = (y3 > 0.f) ? y3 : expm1f(y3);
  if (apk) {
    union { ushort us[4]; unsigned long long u64; } ph, pl;
    ushort h0 = f2bf(o0), h1 = f2bf(o1), h2 = f2bf(o2), h3 = f2bf(o3);
    ph.us[0] = h0; ph.us[1] = h1; ph.us[2] = h2; ph.us[3] = h3;
    pl.us[0] = f2bf(o0 - bf2f(h0)); pl.us[1] = f2bf(o1 - bf2f(h1));
    pl.us[2] = f2bf(o2 - bf2f(h2)); pl.us[3] = f2bf(o3 - bf2f(h3));
    *(unsigned long long*)(apk + (size_t)nid * 512 + ch)       = ph.u64;
    *(unsigned long long*)(apk + (size_t)nid * 512 + 256 + ch) = pl.u64;
  } else {
    floatx4 ov; ov[0] = o0; ov[1] = o1; ov[2] = o2; ov[3] = o3;
    *(floatx4*)(fout + (size_t)nid * HID + ch) = ov;
  }
}

extern "C" void kernel_launch(void* const* d_in, const int* in_sizes, int n_in,
                              void* d_out, int out_size, void* d_ws, size_t ws_size,
                              hipStream_t stream) {
  const float* x  = (const float*)d_in[0];
  const int*   ei = (const int*)d_in[1];
  const float* Wm[3]  = {(const float*)d_in[2], (const float*)d_in[8],  (const float*)d_in[14]};
  const float* Avs[3] = {(const float*)d_in[3], (const float*)d_in[9],  (const float*)d_in[15]};
  const float* Avd[3] = {(const float*)d_in[4], (const float*)d_in[10], (const float*)d_in[16]};
  const float* Bia[3] = {(const float*)d_in[5], (const float*)d_in[11], (const float*)d_in[17]};
  const float* Lnw[3] = {(const float*)d_in[6], (const float*)d_in[12], (const float*)d_in[18]};
  const float* Lnb[3] = {(const float*)d_in[7], (const float*)d_in[13], (const float*)d_in[19]};
  const int n = in_sizes[0] / 512;   // 50000
  const int E = in_sizes[1] / 2;     // 800000
  const int tot = E + n;             // with self-loops
  const int nblk = (n + 1023) / 1024;

  char* p = (char*)d_ws;
  ushort* hb   = (ushort*)p; p += (size_t)n * HID * 2;   // 25.6 MB (bf16 h)
  ushort* apk  = (ushort*)p; p += (size_t)n * 512 * 2;   // 51.2 MB (packed hi|lo act)
  ushort* Wt   = (ushort*)p; p += 256 * 512 * 2;
  float*  asrc = (float*)p;  p += (size_t)n * 4 * 4;
  float*  adst = (float*)p;  p += (size_t)n * 4 * 4;
  int* rp   = (int*)p; p += (size_t)(n + 1) * 4;
  int* cur  = (int*)p; p += (size_t)n * 4;
  int* csr  = (int*)p; p += (size_t)tot * 4;
  int* deg  = (int*)p; p += (size_t)n * 4;
  int* incl = (int*)p; p += (size_t)n * 4;
  int* sums = (int*)p; p += (size_t)(nblk + 1) * 4;
  int* offs = (int*)p; p += (size_t)(nblk + 1) * 4;

  // --- CSR by destination (graph identical for all 3 layers) ---
  hipMemsetAsync(deg, 0, (size_t)n * 4, stream);
  count_kernel<<<(tot + 255) / 256, 256, 0, stream>>>(ei, deg, E, tot);
  scanA_kernel<<<nblk, 1024, 0, stream>>>(deg, incl, sums, n);
  scanB_kernel<<<1, 256, 0, stream>>>(sums, offs, nblk);
  scanC_kernel<<<nblk, 1024, 0, stream>>>(deg, incl, offs, rp, cur, n, nblk);
  scatter_kernel<<<(tot + 255) / 256, 256, 0, stream>>>(ei, cur, csr, E, tot);

  const int KB[3] = {512, 256, 256};
  const int HH[3] = {4, 4, 1};
  dim3 gg((n + 127) / 128, 2);
  for (int l = 0; l < 3; l++) {
    dim3 tg(8, KB[l] / 32);
    transpose_kernel<<<tg, 256, 0, stream>>>(Wm[l], Wt, KB[l]);
    if (l == 0)
      gemm_kernel<<<gg, 256, 0, stream>>>(x, Wt, hb, Avs[l], Avd[l], asrc, adst, n, 512);
    else
      gemm_packed_kernel<<<gg, 256, 0, stream>>>(apk, Wt, hb, Avs[l], Avd[l], asrc, adst, n);
    agg_ln_kernel<<<(n + 3) / 4, 256, 0, stream>>>(
        hb, asrc, adst, rp, csr, Bia[l], Lnw[l], Lnb[l],
        (l < 2) ? apk : (ushort*)nullptr,
        (l == 2) ? (float*)d_out : (float*)nullptr, HH[l], n);
  }
}

// Round 3
// 617.256 us; speedup vs baseline: 1.2104x; 1.2104x over previous
//
#include <hip/hip_runtime.h>

#define HID 256
#define EPSV 1e-5f
#define ASTR 136  // layer-0 At row stride (ushorts): 128 data (hi64|lo64) + 8 pad
#define BSTR 72   // 64 data + 8 pad

typedef __bf16 bf16x8 __attribute__((ext_vector_type(8)));
typedef float  floatx4 __attribute__((ext_vector_type(4)));

static __device__ __forceinline__ ushort f2bf(float f) {
  union { float f; unsigned int i; } c; c.f = f;
  unsigned int u = c.i;
  u += 0x7FFFu + ((u >> 16) & 1u);   // round-to-nearest-even
  return (ushort)(u >> 16);
}
static __device__ __forceinline__ float bf2f(ushort u) {
  union { unsigned int i; float f; } c; c.i = ((unsigned int)u) << 16; return c.f;
}

// ---------------- CSR build ----------------
__global__ void count_kernel(const int* __restrict__ ei, int* __restrict__ deg, int E, int tot) {
  int i = blockIdx.x * blockDim.x + threadIdx.x;
  if (i < tot) {
    int dst = (i < E) ? ei[E + i] : (i - E);
    atomicAdd(&deg[dst], 1);
  }
}

// hierarchical exclusive scan of deg -> rp
__global__ void scanA_kernel(const int* __restrict__ deg, int* __restrict__ incl,
                             int* __restrict__ sums, int n) {
  __shared__ int buf[1024];
  const int t = threadIdx.x;
  const int i = blockIdx.x * 1024 + t;
  int x = (i < n) ? deg[i] : 0;
  buf[t] = x;
  __syncthreads();
  for (int off = 1; off < 1024; off <<= 1) {
    int v = (t >= off) ? buf[t - off] : 0;
    __syncthreads();
    buf[t] += v;
    __syncthreads();
  }
  if (i < n) incl[i] = buf[t];
  if (t == 1023) sums[blockIdx.x] = buf[1023];
}

__global__ void scanB_kernel(int* __restrict__ sums, int* __restrict__ offs, int nblk) {
  __shared__ int buf[256];
  const int t = threadIdx.x;
  int x = (t < nblk) ? sums[t] : 0;
  buf[t] = x;
  __syncthreads();
  for (int off = 1; off < 256; off <<= 1) {
    int v = (t >= off) ? buf[t - off] : 0;
    __syncthreads();
    buf[t] += v;
    __syncthreads();
  }
  if (t < nblk) offs[t] = buf[t] - x;   // exclusive
  if (t == nblk) offs[nblk] = buf[nblk - 1];  // grand total
}

__global__ void scanC_kernel(const int* __restrict__ deg, const int* __restrict__ incl,
                             const int* __restrict__ offs, int* __restrict__ rp,
                             int* __restrict__ cur, int n, int nblk) {
  const int i = blockIdx.x * 1024 + threadIdx.x;
  if (i < n) {
    int v = offs[blockIdx.x] + incl[i] - deg[i];
    rp[i] = v;
    cur[i] = v;
  }
  if (i == 0) rp[n] = offs[nblk];
}

__global__ void scatter_kernel(const int* __restrict__ ei, int* __restrict__ cur,
                               int* __restrict__ csr, int E, int tot) {
  int i = blockIdx.x * blockDim.x + threadIdx.x;
  if (i < tot) {
    int src = (i < E) ? ei[i] : (i - E);
    int dst = (i < E) ? ei[E + i] : (i - E);
    int pos = atomicAdd(&cur[dst], 1);
    csr[pos] = src;
  }
}

// ---------------- W transpose + bf16 cast: f32 [K][256] -> bf16 [256][K] ----------------
// LDS-tiled 32x32: coalesced reads AND writes.
__global__ __launch_bounds__(256) void transpose_kernel(
    const float* __restrict__ W, ushort* __restrict__ Wt, int K) {
  __shared__ ushort tile[32][33];
  const int tx = threadIdx.x & 31, ty = threadIdx.x >> 5;   // 32 x 8
  const int bm = blockIdx.x * 32;   // m block (cols of W, rows of Wt)
  const int bk = blockIdx.y * 32;   // k block
  #pragma unroll
  for (int yy = ty; yy < 32; yy += 8)
    tile[tx][yy] = f2bf(W[(size_t)(bk + yy) * 256 + bm + tx]);
  __syncthreads();
  #pragma unroll
  for (int yy = ty; yy < 32; yy += 8)
    Wt[(size_t)(bm + yy) * K + bk + tx] = tile[yy][tx];
}

// ---- fused alpha-dot epilogue: acc rows dotted with a_src/a_dst col-spans ----
// Each wave's row span is 64 consecutive cols. Always writes partial slot
// (col0+wn)>>6 in [0,4): == head for H=4, == 64-col partial for H=1 (agg sums 4).
static __device__ __forceinline__ void alpha_epilogue(
    const floatx4 (&acc)[4][4], const float* __restrict__ avs,
    const float* __restrict__ avd, float* __restrict__ asrc,
    float* __restrict__ adst, int row0, int col0, int wm, int wn,
    int quad, int m16, int nrows) {
  float sv[4], dv[4];
  #pragma unroll
  for (int j = 0; j < 4; j++) {
    int col = col0 + wn + j * 16 + m16;
    sv[j] = avs[col];
    dv[j] = avd[col];
  }
  const int idx = (col0 + wn) >> 6;   // 0..3
  #pragma unroll
  for (int i = 0; i < 4; i++) {
    #pragma unroll
    for (int r = 0; r < 4; r++) {
      int row = row0 + wm + i * 16 + quad * 4 + r;
      float s = 0.f, d = 0.f;
      #pragma unroll
      for (int j = 0; j < 4; j++) {
        s = fmaf(acc[i][j][r], sv[j], s);
        d = fmaf(acc[i][j][r], dv[j], d);
      }
      #pragma unroll
      for (int o = 1; o < 16; o <<= 1) { s += __shfl_xor(s, o); d += __shfl_xor(d, o); }
      if (m16 == 0 && row < nrows) {
        asrc[row * 4 + idx] = s;
        adst[row * 4 + idx] = d;
      }
    }
  }
}

// ---------------- GEMM (layer 0): hb = A_f32[nrows,512] @ W ----------------
// BK=64: 8 barrier steps instead of 16 (halved barrier/latency exposure, 64
// MFMA per step). Staging loads go to short-lived locals (all 8 A-loads + 4
// B-loads in flight), dead before the barrier -> no cross-barrier spill
// (round-2 lesson: held-across-barrier prefetch regs spilled to scratch,
// WRITE_SIZE 28->80 MB). hi/lo split via truncation + v_perm (proven correct).
__global__ __launch_bounds__(256) void gemm_kernel(
    const float* __restrict__ A, const ushort* __restrict__ Bt,
    ushort* __restrict__ hb, const float* __restrict__ avs,
    const float* __restrict__ avd, float* __restrict__ asrc,
    float* __restrict__ adst, int nrows, int K) {
  __shared__ ushort At[128 * ASTR];   // 34.8 KB
  __shared__ ushort Bs[128 * BSTR];   // 18.4 KB
  const int tid  = threadIdx.x;
  const int lane = tid & 63;
  const int wave = tid >> 6;
  const int quad = lane >> 4;
  const int m16  = lane & 15;
  const int row0 = blockIdx.x * 128;
  const int col0 = blockIdx.y * 128;
  const int wm = (wave >> 1) * 64;
  const int wn = (wave & 1) * 64;

  floatx4 acc[4][4];
  #pragma unroll
  for (int i = 0; i < 4; i++)
    #pragma unroll
    for (int j = 0; j < 4; j++) acc[i][j] = (floatx4){0.f, 0.f, 0.f, 0.f};

  const int arow = tid >> 3;         // 0..31
  const int acol = (tid & 7) * 4;    // 0..28
  const int brow = tid >> 2;         // 0..63
  const int bcol = (tid & 3) * 8;    // 0..24

  for (int k0 = 0; k0 < K; k0 += 64) {
    // load phase: all loads issued before any convert/store (MLP=12)
    floatx4 va[4][2];
    int4 vb[2][2];
    #pragma unroll
    for (int i = 0; i < 4; i++) {
      int ar = min(row0 + arow + 32 * i, nrows - 1);
      #pragma unroll
      for (int c = 0; c < 2; c++)
        va[i][c] = *(const floatx4*)(A + (size_t)ar * K + k0 + c * 32 + acol);
    }
    #pragma unroll
    for (int i = 0; i < 2; i++) {
      int r = brow + 64 * i;
      #pragma unroll
      for (int c = 0; c < 2; c++)
        vb[i][c] = *(const int4*)(Bt + (size_t)(col0 + r) * K + k0 + c * 32 + bcol);
    }
    // convert + stage
    #pragma unroll
    for (int i = 0; i < 4; i++) {
      int r = arow + 32 * i;
      #pragma unroll
      for (int c = 0; c < 2; c++) {
        floatx4 v = va[i][c];
        unsigned u0 = __float_as_uint(v[0]), u1 = __float_as_uint(v[1]);
        unsigned u2 = __float_as_uint(v[2]), u3 = __float_as_uint(v[3]);
        unsigned ph0 = __builtin_amdgcn_perm(u1, u0, 0x07060302u);
        unsigned ph1 = __builtin_amdgcn_perm(u3, u2, 0x07060302u);
        float l0 = v[0] - __uint_as_float(u0 & 0xffff0000u);
        float l1 = v[1] - __uint_as_float(u1 & 0xffff0000u);
        float l2 = v[2] - __uint_as_float(u2 & 0xffff0000u);
        float l3 = v[3] - __uint_as_float(u3 & 0xffff0000u);
        unsigned pl0 = __builtin_amdgcn_perm(__float_as_uint(l1), __float_as_uint(l0), 0x07060302u);
        unsigned pl1 = __builtin_amdgcn_perm(__float_as_uint(l3), __float_as_uint(l2), 0x07060302u);
        *(uint2*)&At[r * ASTR + c * 32 + acol]      = make_uint2(ph0, ph1);
        *(uint2*)&At[r * ASTR + 64 + c * 32 + acol] = make_uint2(pl0, pl1);
      }
    }
    #pragma unroll
    for (int i = 0; i < 2; i++) {
      int r = brow + 64 * i;
      #pragma unroll
      for (int c = 0; c < 2; c++)
        *(int4*)&Bs[r * BSTR + c * 32 + bcol] = vb[i][c];
    }
    __syncthreads();
    // compute: 2 k-subchunks x (hi,lo) x 16 MFMA = 64 MFMA per step
    #pragma unroll
    for (int kk = 0; kk < 2; kk++) {
      bf16x8 bfr[4];
      #pragma unroll
      for (int j = 0; j < 4; j++)
        bfr[j] = *(const bf16x8*)&Bs[(wn + j * 16 + m16) * BSTR + kk * 32 + quad * 8];
      #pragma unroll
      for (int p = 0; p < 2; p++) {
        bf16x8 af[4];
        #pragma unroll
        for (int i = 0; i < 4; i++)
          af[i] = *(const bf16x8*)&At[(wm + i * 16 + m16) * ASTR + p * 64 + kk * 32 + quad * 8];
        #pragma unroll
        for (int i = 0; i < 4; i++)
          #pragma unroll
          for (int j = 0; j < 4; j++)
            acc[i][j] = __builtin_amdgcn_mfma_f32_16x16x32_bf16(af[i], bfr[j], acc[i][j], 0, 0, 0);
      }
    }
    __syncthreads();
  }
  #pragma unroll
  for (int i = 0; i < 4; i++) {
    int rbase = row0 + wm + i * 16 + quad * 4;
    #pragma unroll
    for (int j = 0; j < 4; j++) {
      int col = col0 + wn + j * 16 + m16;
      #pragma unroll
      for (int r = 0; r < 4; r++) {
        int row = rbase + r;
        if (row < nrows) hb[(size_t)row * HID + col] = f2bf(acc[i][j][r]);
      }
    }
  }
  alpha_epilogue(acc, avs, avd, asrc, adst, row0, col0, wm, wn, quad, m16, nrows);
}

// ---------------- GEMM (layers 1-2): hb = apk[nrows,512](hi|lo) @ W-replicated ----------------
// BK=64: 8 steps, 32 MFMA/step, 8 loads in flight, no cross-barrier regs.
__global__ __launch_bounds__(256) void gemm_packed_kernel(
    const ushort* __restrict__ A, const ushort* __restrict__ Bt,
    ushort* __restrict__ hb, const float* __restrict__ avs,
    const float* __restrict__ avd, float* __restrict__ asrc,
    float* __restrict__ adst, int nrows) {
  __shared__ ushort At[128 * BSTR];   // 18.4 KB
  __shared__ ushort Bs[128 * BSTR];   // 18.4 KB
  const int tid  = threadIdx.x;
  const int lane = tid & 63;
  const int wave = tid >> 6;
  const int quad = lane >> 4;
  const int m16  = lane & 15;
  const int row0 = blockIdx.x * 128;
  const int col0 = blockIdx.y * 128;
  const int wm = (wave >> 1) * 64;
  const int wn = (wave & 1) * 64;

  floatx4 acc[4][4];
  #pragma unroll
  for (int i = 0; i < 4; i++)
    #pragma unroll
    for (int j = 0; j < 4; j++) acc[i][j] = (floatx4){0.f, 0.f, 0.f, 0.f};

  const int srow = tid >> 2;        // 0..63
  const int scol = (tid & 3) * 8;   // 0..24

  for (int k0 = 0; k0 < 512; k0 += 64) {
    const int kb = k0 & 255;
    int4 va[2][2], vb[2][2];
    #pragma unroll
    for (int i = 0; i < 2; i++) {
      int r = srow + 64 * i;
      int ar = min(row0 + r, nrows - 1);
      #pragma unroll
      for (int c = 0; c < 2; c++) {
        va[i][c] = *(const int4*)(A + (size_t)ar * 512 + k0 + c * 32 + scol);
        vb[i][c] = *(const int4*)(Bt + (size_t)(col0 + r) * 256 + kb + c * 32 + scol);
      }
    }
    #pragma unroll
    for (int i = 0; i < 2; i++) {
      int r = srow + 64 * i;
      #pragma unroll
      for (int c = 0; c < 2; c++) {
        *(int4*)&At[r * BSTR + c * 32 + scol] = va[i][c];
        *(int4*)&Bs[r * BSTR + c * 32 + scol] = vb[i][c];
      }
    }
    __syncthreads();
    #pragma unroll
    for (int kk = 0; kk < 2; kk++) {
      bf16x8 af[4], bfr[4];
      #pragma unroll
      for (int j = 0; j < 4; j++)
        bfr[j] = *(const bf16x8*)&Bs[(wn + j * 16 + m16) * BSTR + kk * 32 + quad * 8];
      #pragma unroll
      for (int i = 0; i < 4; i++)
        af[i] = *(const bf16x8*)&At[(wm + i * 16 + m16) * BSTR + kk * 32 + quad * 8];
      #pragma unroll
      for (int i = 0; i < 4; i++)
        #pragma unroll
        for (int j = 0; j < 4; j++)
          acc[i][j] = __builtin_amdgcn_mfma_f32_16x16x32_bf16(af[i], bfr[j], acc[i][j], 0, 0, 0);
    }
    __syncthreads();
  }
  #pragma unroll
  for (int i = 0; i < 4; i++) {
    int rbase = row0 + wm + i * 16 + quad * 4;
    #pragma unroll
    for (int j = 0; j < 4; j++) {
      int col = col0 + wn + j * 16 + m16;
      #pragma unroll
      for (int r = 0; r < 4; r++) {
        int row = rbase + r;
        if (row < nrows) hb[(size_t)row * HID + col] = f2bf(acc[i][j][r]);
      }
    }
  }
  alpha_epilogue(acc, avs, avd, asrc, adst, row0, col0, wm, wn, quad, m16, nrows);
}

// ---- fused segment softmax + aggregation + bias + LayerNorm + ELU ----
// ONE WAVE PER NODE, 4 ch/lane. Phase B unrolled x4 (4 gathers in flight).
// For H=1, asrc/adst hold 4 partials per node (written by alpha_epilogue)
// -> summed here; no atomics, no memset.
__global__ __launch_bounds__(256) void agg_ln_kernel(
    const ushort* __restrict__ hb, const float* __restrict__ asrc,
    const float* __restrict__ adst, const int* __restrict__ rp,
    const int* __restrict__ csr,
    const float* __restrict__ bias, const float* __restrict__ lnw,
    const float* __restrict__ lnb, ushort* __restrict__ apk,
    float* __restrict__ fout, int H, int n) {
  __shared__ float2 exs[4][64];
  const int t = threadIdx.x;
  const int w = t >> 6, lane = t & 63;
  const int nid = blockIdx.x * 4 + w;
  if (nid >= n) return;
  const int CH = (H == 4) ? 16 : 64;   // edges per chunk
  const int jj = lane & (CH - 1);
  const int hh = (H == 4) ? (lane >> 4) : 0;
  const int ch = 4 * lane;
  float ad;
  if (H == 4) {
    ad = adst[nid * 4 + hh];
  } else {
    floatx4 t4 = *(const floatx4*)(adst + nid * 4);
    ad = t4[0] + t4[1] + t4[2] + t4[3];
  }
  const int beg = rp[nid], end = rp[nid + 1];
  const char* hbase = (const char*)hb + ch * 2;
  float den = 0.f;
  float a0 = 0.f, a1 = 0.f, a2 = 0.f, a3 = 0.f;
  float b0 = 0.f, b1 = 0.f, b2 = 0.f, b3 = 0.f;
  float c0_ = 0.f, c1 = 0.f, c2 = 0.f, c3 = 0.f;
  float d0_ = 0.f, d1 = 0.f, d2 = 0.f, d3 = 0.f;

  // preload first chunk's csr
  int snext = 0;
  {
    int cnt0 = min(CH, end - beg);
    if (lane < cnt0) snext = csr[beg + lane];
  }

  for (int c0 = beg; c0 < end; c0 += CH) {
    const int cnt = min(CH, end - c0);
    int s = snext;
    // prefetch next chunk's csr while this chunk computes
    const int nc0 = c0 + CH;
    if (nc0 < end) {
      int ncnt = min(CH, end - nc0);
      if (lane < ncnt) snext = csr[nc0 + lane];
    }
    // phase A
    s = __shfl(s, jj);
    float ex = 0.f;
    if (jj < cnt) {
      float e;
      if (H == 4) {
        e = asrc[s * 4 + hh] + ad;
      } else {
        floatx4 t4 = *(const floatx4*)(asrc + s * 4);
        e = t4[0] + t4[1] + t4[2] + t4[3] + ad;
      }
      e = (e > 0.f) ? e : 0.2f * e;    // leaky_relu 0.2
      ex = __expf(fminf(e, 60.f));
    }
    exs[w][lane] = make_float2(ex, __int_as_float(s << 9));
    float dsum = ex;
    #pragma unroll
    for (int o = 32; o > 0; o >>= 1)
      if (o < CH) dsum += __shfl_xor(dsum, o);
    den += dsum;
    // phase B: unroll x4, 4 accumulator quads, 4 gathers in flight
    const float2* exw = &exs[w][hh * CH];
    int j = 0;
    for (; j + 4 <= cnt; j += 4) {
      float2 q0 = exw[j];
      float2 q1 = exw[j + 1];
      float2 q2 = exw[j + 2];
      float2 q3 = exw[j + 3];
      uint2 u0 = *(const uint2*)(hbase + __float_as_int(q0.y));
      uint2 u1 = *(const uint2*)(hbase + __float_as_int(q1.y));
      uint2 u2 = *(const uint2*)(hbase + __float_as_int(q2.y));
      uint2 u3 = *(const uint2*)(hbase + __float_as_int(q3.y));
      a0 = fmaf(q0.x, __uint_as_float(u0.x << 16), a0);
      a1 = fmaf(q0.x, __uint_as_float(u0.x & 0xffff0000u), a1);
      a2 = fmaf(q0.x, __uint_as_float(u0.y << 16), a2);
      a3 = fmaf(q0.x, __uint_as_float(u0.y & 0xffff0000u), a3);
      b0 = fmaf(q1.x, __uint_as_float(u1.x << 16), b0);
      b1 = fmaf(q1.x, __uint_as_float(u1.x & 0xffff0000u), b1);
      b2 = fmaf(q1.x, __uint_as_float(u1.y << 16), b2);
      b3 = fmaf(q1.x, __uint_as_float(u1.y & 0xffff0000u), b3);
      c0_ = fmaf(q2.x, __uint_as_float(u2.x << 16), c0_);
      c1 = fmaf(q2.x, __uint_as_float(u2.x & 0xffff0000u), c1);
      c2 = fmaf(q2.x, __uint_as_float(u2.y << 16), c2);
      c3 = fmaf(q2.x, __uint_as_float(u2.y & 0xffff0000u), c3);
      d0_ = fmaf(q3.x, __uint_as_float(u3.x << 16), d0_);
      d1 = fmaf(q3.x, __uint_as_float(u3.x & 0xffff0000u), d1);
      d2 = fmaf(q3.x, __uint_as_float(u3.y << 16), d2);
      d3 = fmaf(q3.x, __uint_as_float(u3.y & 0xffff0000u), d3);
    }
    for (; j < cnt; ++j) {
      float2 q0 = exw[j];
      uint2 u0 = *(const uint2*)(hbase + __float_as_int(q0.y));
      a0 = fmaf(q0.x, __uint_as_float(u0.x << 16), a0);
      a1 = fmaf(q0.x, __uint_as_float(u0.x & 0xffff0000u), a1);
      a2 = fmaf(q0.x, __uint_as_float(u0.y << 16), a2);
      a3 = fmaf(q0.x, __uint_as_float(u0.y & 0xffff0000u), a3);
    }
  }
  a0 += b0 + c0_ + d0_;
  a1 += b1 + c1 + d1;
  a2 += b2 + c2 + d2;
  a3 += b3 + c3 + d3;

  // epilogue: bias + LN + ELU (wave-local, barrier-free)
  const float inv = 1.f / den;
  const floatx4 bia = *(const floatx4*)(bias + ch);
  float v0 = a0 * inv + bia[0];
  float v1 = a1 * inv + bia[1];
  float v2 = a2 * inv + bia[2];
  float v3 = a3 * inv + bia[3];
  float r1 = v0 + v1 + v2 + v3;
  #pragma unroll
  for (int o = 32; o > 0; o >>= 1) r1 += __shfl_xor(r1, o);
  float mu = r1 * (1.f / HID);
  float e0 = v0 - mu, e1 = v1 - mu, e2 = v2 - mu, e3 = v3 - mu;
  float r2 = e0 * e0 + e1 * e1 + e2 * e2 + e3 * e3;
  #pragma unroll
  for (int o = 32; o > 0; o >>= 1) r2 += __shfl_xor(r2, o);
  float rstd = rsqrtf(r2 * (1.f / HID) + EPSV);
  const floatx4 wv = *(const floatx4*)(lnw + ch);
  const floatx4 bv = *(const floatx4*)(lnb + ch);
  float y0 = e0 * rstd * wv[0] + bv[0];
  float y1 = e1 * rstd * wv[1] + bv[1];
  float y2 = e2 * rstd * wv[2] + bv[2];
  float y3 = e3 * rstd * wv[3] + bv[3];
  float o0 = (y0 > 0.f) ? y0 : expm1f(y0);   // ELU
  float o1 = (y1 > 0.f) ? y1 : expm1f(y1);
  float o2 = (y2 > 0.f) ? y2 : expm1f(y2);
  float o3 = (y3 > 0.f) ? y3 : expm1f(y3);
  if (apk) {
    union { ushort us[4]; unsigned long long u64; } ph, pl;
    ushort h0 = f2bf(o0), h1 = f2bf(o1), h2 = f2bf(o2), h3 = f2bf(o3);
    ph.us[0] = h0; ph.us[1] = h1; ph.us[2] = h2; ph.us[3] = h3;
    pl.us[0] = f2bf(o0 - bf2f(h0)); pl.us[1] = f2bf(o1 - bf2f(h1));
    pl.us[2] = f2bf(o2 - bf2f(h2)); pl.us[3] = f2bf(o3 - bf2f(h3));
    *(unsigned long long*)(apk + (size_t)nid * 512 + ch)       = ph.u64;
    *(unsigned long long*)(apk + (size_t)nid * 512 + 256 + ch) = pl.u64;
  } else {
    floatx4 ov; ov[0] = o0; ov[1] = o1; ov[2] = o2; ov[3] = o3;
    *(floatx4*)(fout + (size_t)nid * HID + ch) = ov;
  }
}

extern "C" void kernel_launch(void* const* d_in, const int* in_sizes, int n_in,
                              void* d_out, int out_size, void* d_ws, size_t ws_size,
                              hipStream_t stream) {
  const float* x  = (const float*)d_in[0];
  const int*   ei = (const int*)d_in[1];
  const float* Wm[3]  = {(const float*)d_in[2], (const float*)d_in[8],  (const float*)d_in[14]};
  const float* Avs[3] = {(const float*)d_in[3], (const float*)d_in[9],  (const float*)d_in[15]};
  const float* Avd[3] = {(const float*)d_in[4], (const float*)d_in[10], (const float*)d_in[16]};
  const float* Bia[3] = {(const float*)d_in[5], (const float*)d_in[11], (const float*)d_in[17]};
  const float* Lnw[3] = {(const float*)d_in[6], (const float*)d_in[12], (const float*)d_in[18]};
  const float* Lnb[3] = {(const float*)d_in[7], (const float*)d_in[13], (const float*)d_in[19]};
  const int n = in_sizes[0] / 512;   // 50000
  const int E = in_sizes[1] / 2;     // 800000
  const int tot = E + n;             // with self-loops
  const int nblk = (n + 1023) / 1024;

  char* p = (char*)d_ws;
  ushort* hb   = (ushort*)p; p += (size_t)n * HID * 2;   // 25.6 MB (bf16 h)
  ushort* apk  = (ushort*)p; p += (size_t)n * 512 * 2;   // 51.2 MB (packed hi|lo act)
  ushort* Wt   = (ushort*)p; p += 256 * 512 * 2;
  float*  asrc = (float*)p;  p += (size_t)n * 4 * 4;
  float*  adst = (float*)p;  p += (size_t)n * 4 * 4;
  int* rp   = (int*)p; p += (size_t)(n + 1) * 4;
  int* cur  = (int*)p; p += (size_t)n * 4;
  int* csr  = (int*)p; p += (size_t)tot * 4;
  int* deg  = (int*)p; p += (size_t)n * 4;
  int* incl = (int*)p; p += (size_t)n * 4;
  int* sums = (int*)p; p += (size_t)(nblk + 1) * 4;
  int* offs = (int*)p; p += (size_t)(nblk + 1) * 4;

  // --- CSR by destination (graph identical for all 3 layers) ---
  hipMemsetAsync(deg, 0, (size_t)n * 4, stream);
  count_kernel<<<(tot + 255) / 256, 256, 0, stream>>>(ei, deg, E, tot);
  scanA_kernel<<<nblk, 1024, 0, stream>>>(deg, incl, sums, n);
  scanB_kernel<<<1, 256, 0, stream>>>(sums, offs, nblk);
  scanC_kernel<<<nblk, 1024, 0, stream>>>(deg, incl, offs, rp, cur, n, nblk);
  scatter_kernel<<<(tot + 255) / 256, 256, 0, stream>>>(ei, cur, csr, E, tot);

  const int KB[3] = {512, 256, 256};
  const int HH[3] = {4, 4, 1};
  dim3 gg((n + 127) / 128, 2);
  for (int l = 0; l < 3; l++) {
    dim3 tg(8, KB[l] / 32);
    transpose_kernel<<<tg, 256, 0, stream>>>(Wm[l], Wt, KB[l]);
    if (l == 0)
      gemm_kernel<<<gg, 256, 0, stream>>>(x, Wt, hb, Avs[l], Avd[l], asrc, adst, n, 512);
    else
      gemm_packed_kernel<<<gg, 256, 0, stream>>>(apk, Wt, hb, Avs[l], Avd[l], asrc, adst, n);
    agg_ln_kernel<<<(n + 3) / 4, 256, 0, stream>>>(
        hb, asrc, adst, rp, csr, Bia[l], Lnw[l], Lnb[l],
        (l < 2) ? apk : (ushort*)nullptr,
        (l == 2) ? (float*)d_out : (float*)nullptr, HH[l], n);
  }
}